// Round 9
// baseline (247.234 us; speedup 1.0000x reference)
//
#include <hip/hip_runtime.h>
#include <stdint.h>
#include <math.h>

// ---------------------------------------------------------------------------
// Generator_44555990728950. B=4096 molecules, N=32 nodes (chain), H=128,
// 16 GAT layers. All 32 nodes of a molecule are identical through the GAT
// stack (broadcast init + attention weights sum to 1 over identical
// neighbors), so: layer = relu(x + x@W + b), one class per molecule.
// R15: M=2 per wave + readlane broadcast + 2 waves/SIMD TLP.
//   R14 post-mortem: readlane main loop is VALU-dominated (VALUBusy 60%,
//   ~51us/SIMD issue floor) but 1 wave/SIMD (grid=256=1 block/CU) leaves
//   ~45% stalls unhidden. M=2 -> 512 blocks = 2 blocks/CU = 2 waves/SIMD:
//   per-SIMD VALU ~58us, per-CU VMEM ~58us (8 waves stream W in phase ->
//   L1 hits), DS ~0, 2-way TLP hides the rest. Registers DROP vs R14
//   (4 accumulators, same float2[8]x2 W buffers) -- inside the proven
//   no-spill envelope (R13: VGPR=56 at this shape).
// Deterministic pipeline fp64 (accumulation order unchanged); JAX
// partitionable threefry bit-exact; outputs fp32.
// ---------------------------------------------------------------------------

struct U2 { uint32_t a, b; };

// Threefry-2x32, 20 rounds, exactly as jax._src.prng
__device__ __forceinline__ U2 threefry(uint32_t k0, uint32_t k1, uint32_t x0, uint32_t x1) {
  const uint32_t ks2 = k0 ^ k1 ^ 0x1BD11BDAu;
#define TFR(r) { x0 += x1; x1 = (x1 << (r)) | (x1 >> (32 - (r))); x1 ^= x0; }
  x0 += k0;  x1 += k1;
  TFR(13) TFR(15) TFR(26) TFR(6)
  x0 += k1;  x1 += ks2 + 1u;
  TFR(17) TFR(29) TFR(16) TFR(24)
  x0 += ks2; x1 += k0 + 2u;
  TFR(13) TFR(15) TFR(26) TFR(6)
  x0 += k0;  x1 += k1 + 3u;
  TFR(17) TFR(29) TFR(16) TFR(24)
  x0 += k1;  x1 += ks2 + 4u;
  TFR(13) TFR(15) TFR(26) TFR(6)
  x0 += ks2; x1 += k0 + 5u;
#undef TFR
  U2 r; r.a = x0; r.b = x1; return r;
}

// partitionable random_bits, 32-bit: counter = flat index; fold o1^o2
__device__ __forceinline__ uint32_t pbits(uint32_t k0, uint32_t k1, uint32_t ctr) {
  U2 r = threefry(k0, k1, 0u, ctr);
  return r.a ^ r.b;
}

__device__ __forceinline__ float bits_to_unit(uint32_t bits) {
  return __uint_as_float((bits >> 9) | 0x3f800000u) - 1.0f;  // [0,1)
}

// f32 uniform(1e-6, 1-1e-6) -> gumbel, exactly jax's f32 path
__device__ __forceinline__ float jgumbel(uint32_t k0, uint32_t k1, uint32_t ctr) {
  const float minv = 1e-6f;
  const float maxv = (float)(1.0 - 1e-6);
  const float span = maxv - minv;
  float f = bits_to_unit(pbits(k0, k1, ctr));
  float u = fmaxf(minv, __fadd_rn(__fmul_rn(f, span), minv));
  return -logf(-logf(u));
}

// wave-broadcast a double from a given lane (compile-time lane after unroll)
__device__ __forceinline__ double rl_bcast(double v, int lane) {
  union { double d; unsigned int u[2]; } c; c.d = v;
  unsigned int lo = __builtin_amdgcn_readlane(c.u[0], lane);
  unsigned int hi = __builtin_amdgcn_readlane(c.u[1], lane);
  union { double d; unsigned int u[2]; } r; r.u[0] = lo; r.u[1] = hi;
  return r.d;
}

extern "C" __global__ void __launch_bounds__(256)
gen_kernel(const float* __restrict__ noise,
           const float* __restrict__ w1,
           const float* __restrict__ b1,
           const float* __restrict__ gat_w,
           const float* __restrict__ gat_b,
           const float* __restrict__ w_atom,
           const float* __restrict__ b_atom,
           const float* __restrict__ w_hyb,
           const float* __restrict__ b_hyb,
           const float* __restrict__ w_deg,
           const float* __restrict__ b_deg,
           const float* __restrict__ w_chg,
           const float* __restrict__ b_chg,
           const float* __restrict__ w_arom,
           const float* __restrict__ b_arom,
           const float* __restrict__ w_eex,
           const float* __restrict__ b_eex,
           const float* __restrict__ w_ety,
           const float* __restrict__ b_ety,
           float* __restrict__ out)
{
  // LDS used ONLY by the head/sampling phases (wave-private, no barriers).
  __shared__ __align__(16) double sX[4][128][2];   // x after 17 layers, 8 KB
  __shared__ double sScr[4][2][16];                // head logits, 1 KB
  __shared__ float  sNF[4][2][32][17];             // node features, 17.4 KB
  __shared__ double sLP[4][2][64];                 // lp scratch, 4 KB

  const int t       = threadIdx.x;
  const int wv      = t >> 6;
  const int ln      = t & 63;
  const int molPair = (blockIdx.x * 4 + wv) * 2;   // wave owns mols molPair, +1
  const int c0      = ln << 1;                     // lane's two columns

  // x state entirely in registers: xm = {x[c0], x[c0+1]} per mol
  double2 x0, x1;

  // ---------------- stage noise directly into x registers
  {
    const float2 n0 = *(const float2*)(noise + (size_t)molPair * 128 + c0);
    const float2 n1 = *(const float2*)(noise + (size_t)(molPair + 1) * 128 + c0);
    x0.x = (double)n0.x; x0.y = (double)n0.y;
    x1.x = (double)n1.x; x1.y = (double)n1.y;
  }

  // ---------------- 17 unified layers:
  //   l==0 : x = relu(noise @ w1 + b1)        (input = x regs, no residual)
  //   l>=1 : x = relu(x + x@W_l + b_l)
  // W loads: 2-stage pipeline, chunks of 8 k-iters. x broadcast: readlane.
  #pragma unroll 1
  for (int l = 0; l < 17; ++l) {
    const float* __restrict__ W  = (l == 0) ? w1 : (gat_w + (((size_t)(l - 1)) << 14));
    const float* __restrict__ bp = (l == 0) ? b1 : (gat_b + ((l - 1) << 7));

    double a0x = 0.0, a0y = 0.0, a1x = 0.0, a1y = 0.0;

    float2 wA[8], wB[8];

    // prologue: chunk 0 -> buffer A
    #pragma unroll
    for (int j = 0; j < 8; ++j)
      wA[j] = *(const float2*)(W + (j << 7) + c0);

    #pragma unroll
    for (int ch = 0; ch < 16; ++ch) {
      const int nb = (ch + 1) << 3;                 // next chunk base (compile-time)
      if ((ch & 1) == 0) {
        if (ch < 15) {
          #pragma unroll
          for (int j = 0; j < 8; ++j)
            wB[j] = *(const float2*)(W + ((nb + j) << 7) + c0);
        }
        #pragma unroll
        for (int j = 0; j < 8; ++j) {
          const int k    = (ch << 3) + j;           // compile-time
          const int lane = k >> 1;
          const double xa0 = rl_bcast((k & 1) ? x0.y : x0.x, lane);
          const double xa1 = rl_bcast((k & 1) ? x1.y : x1.x, lane);
          const double wx = (double)wA[j].x, wy = (double)wA[j].y;
          a0x = fma(xa0, wx, a0x); a0y = fma(xa0, wy, a0y);
          a1x = fma(xa1, wx, a1x); a1y = fma(xa1, wy, a1y);
        }
      } else {
        if (ch < 15) {
          #pragma unroll
          for (int j = 0; j < 8; ++j)
            wA[j] = *(const float2*)(W + ((nb + j) << 7) + c0);
        }
        #pragma unroll
        for (int j = 0; j < 8; ++j) {
          const int k    = (ch << 3) + j;           // compile-time
          const int lane = k >> 1;
          const double xa0 = rl_bcast((k & 1) ? x0.y : x0.x, lane);
          const double xa1 = rl_bcast((k & 1) ? x1.y : x1.x, lane);
          const double wx = (double)wB[j].x, wy = (double)wB[j].y;
          a0x = fma(xa0, wx, a0x); a0y = fma(xa0, wy, a0y);
          a1x = fma(xa1, wx, a1x); a1y = fma(xa1, wy, a1y);
        }
      }
    }

    const float2 bb = *(const float2*)(bp + c0);
    const double bx = (double)bb.x, by = (double)bb.y;
    if (l == 0) {
      x0.x = fmax(a0x + bx, 0.0); x0.y = fmax(a0y + by, 0.0);
      x1.x = fmax(a1x + bx, 0.0); x1.y = fmax(a1y + by, 0.0);
    } else {
      x0.x = fmax(x0.x + a0x + bx, 0.0); x0.y = fmax(x0.y + a0y + by, 0.0);
      x1.x = fmax(x1.x + a1x + bx, 0.0); x1.y = fmax(x1.y + a1y + by, 0.0);
    }
  }

  // ---------------- publish x to LDS for the head phases (wave-private)
  {
    double2 v;
    v.x = x0.x; v.y = x1.x; *(double2*)&sX[wv][c0][0]     = v;
    v.x = x0.y; v.y = x1.y; *(double2*)&sX[wv][c0 + 1][0] = v;
  }

  // ---------------- phase A: head logits (lanes 0..31 = 2 mols x 16 heads)
  if (ln < 32) {
    const int mh = ln >> 4;            // 0..1
    const int h  = ln & 15;            // head index
    const double* xsrc = &sX[wv][0][mh];
    const float* wp; int stride; double bias;
    if (h < 10)       { wp = w_atom + h;        stride = 10; bias = (double)b_atom[h]; }
    else if (h < 13)  { wp = w_hyb + (h - 10);  stride = 3;  bias = (double)b_hyb[h - 10]; }
    else if (h == 13) { wp = w_deg;             stride = 1;  bias = (double)b_deg[0]; }
    else if (h == 14) { wp = w_chg;             stride = 1;  bias = (double)b_chg[0]; }
    else              { wp = w_arom;            stride = 1;  bias = (double)b_arom[0]; }
    double acc = 0.0;
    for (int c = 0; c < 128; ++c)
      acc = fma(xsrc[(size_t)c * 2], (double)wp[c * stride], acc);
    sScr[wv][mh][h] = acc + bias;
  }

  // partitionable split(key(42),4): child_i = threefry((0,42),(0,i))
  const U2 k0p = threefry(0u, 42u, 0u, 0u);
  const U2 k1p = threefry(0u, 42u, 0u, 1u);
  const U2 k2p = threefry(0u, 42u, 0u, 2u);
  const U2 k3p = threefry(0u, 42u, 0u, 3u);

  // ---------------- phase B: per-node sampling, 64 lanes = 2 mols x 32 nodes
  {
    const int mh  = ln >> 5;
    const int n   = ln & 31;
    const int mol = molPair + mh;
    const double* scr = sScr[wv][mh];     // same logits for every node

    double m = scr[0];
    #pragma unroll
    for (int a = 1; a < 10; ++a) m = fmax(m, scr[a]);
    double lsum = 0.0;
    #pragma unroll
    for (int a = 0; a < 10; ++a) lsum += exp(scr[a] - m);
    const double lse = log(lsum);
    const uint32_t abase = ((uint32_t)mol * 32u + (uint32_t)n) * 10u;
    int asel = 0; double abest = 0.0;
    #pragma unroll
    for (int a = 0; a < 10; ++a) {
      const double g = (double)jgumbel(k0p.a, k0p.b, abase + (uint32_t)a);
      const double sc = scr[a] + g;
      if (a == 0 || sc > abest) { abest = sc; asel = a; }
    }
    sLP[wv][mh][n] = (scr[asel] - m) - lse;

    double m2 = fmax(fmax(scr[10], scr[11]), scr[12]);
    double ls2 = exp(scr[10] - m2) + exp(scr[11] - m2) + exp(scr[12] - m2);
    const double lse2 = log(ls2);
    const uint32_t hbase = ((uint32_t)mol * 32u + (uint32_t)n) * 3u;
    int hsel = 0; double hbest = 0.0;
    #pragma unroll
    for (int j = 0; j < 3; ++j) {
      const double g = (double)jgumbel(k1p.a, k1p.b, hbase + (uint32_t)j);
      const double sc = scr[10 + j] + g;
      if (j == 0 || sc > hbest) { hbest = sc; hsel = j; }
    }
    sLP[wv][mh][32 + n] = (scr[10 + hsel] - m2) - lse2;

    const double deg = 1.0 / (1.0 + exp(-scr[13]));
    const double chg = tanh(scr[14]);
    const double pr  = 1.0 / (1.0 + exp(-scr[15]));
    const uint32_t ridx = (uint32_t)mol * 32u + (uint32_t)n;
    const double uu = (double)bits_to_unit(pbits(k2p.a, k2p.b, ridx));
    const double arom = (uu < pr) ? 1.0 : 0.0;
    const double valt[10] = {4.0/5.0, 3.0/5.0, 2.0/5.0, 1.0/5.0, 4.0/5.0,
                             2.0/5.0, 6.0/5.0, 1.0/5.0, 4.0/5.0, 4.0/5.0};
    double nf[17];
    #pragma unroll
    for (int i = 0; i < 10; ++i) nf[i] = (i == asel) ? 1.0 : 0.0;
    nf[10] = deg; nf[11] = chg;
    #pragma unroll
    for (int j = 0; j < 3; ++j) nf[12 + j] = (j == hsel) ? 1.0 : 0.0;
    nf[15] = arom; nf[16] = valt[asel];

    const size_t o = ((size_t)mol * 32 + n) * 17;
    #pragma unroll
    for (int i = 0; i < 17; ++i) {
      sNF[wv][mh][n][i] = (float)nf[i];
      out[o + i] = (float)nf[i];
    }
  }

  // ---------------- phase C: lp means + edge heads, 2 mols sequentially
  #pragma unroll 1
  for (int m = 0; m < 2; ++m) {
    const int mol = molPair + m;
    if (ln == 62) {
      double sa = 0.0;
      for (int n = 0; n < 32; ++n) sa += sLP[wv][m][n];
      out[2228224 + (size_t)mol] = (float)(sa / 32.0);
    } else if (ln == 63) {
      double sh = 0.0;
      for (int n = 0; n < 32; ++n) sh += sLP[wv][m][32 + n];
      out[2232320 + (size_t)mol] = (float)(sh / 32.0);
    } else {
      const int e = ln;                       // 0..61
      const int nu_ = (e < 31) ? e : (e - 30);
      const int nv_ = (e < 31) ? (e + 1) : (e - 31);
      double lex = 0.0;
      double lt[4] = {0.0, 0.0, 0.0, 0.0};
      for (int i = 0; i < 17; ++i) {
        const double f = (double)sNF[wv][m][nu_][i];
        lex = fma(f, (double)w_eex[i], lex);
        #pragma unroll
        for (int c = 0; c < 4; ++c) lt[c] = fma(f, (double)w_ety[i * 4 + c], lt[c]);
      }
      for (int i = 0; i < 17; ++i) {
        const double f = (double)sNF[wv][m][nv_][i];
        lex = fma(f, (double)w_eex[17 + i], lex);
        #pragma unroll
        for (int c = 0; c < 4; ++c) lt[c] = fma(f, (double)w_ety[(17 + i) * 4 + c], lt[c]);
      }
      lex += (double)b_eex[0];
      #pragma unroll
      for (int c = 0; c < 4; ++c) lt[c] += (double)b_ety[c];

      const double pex = 1.0 / (1.0 + exp(-lex));
      out[3252224 + (size_t)mol * 62 + e] = (pex > 0.5) ? 1.f : 0.f;

      const uint32_t tbase = ((uint32_t)mol * 62u + (uint32_t)e) * 4u;
      int tsel = 0; double tbest = 0.0;
      #pragma unroll
      for (int c = 0; c < 4; ++c) {
        const double g = (double)jgumbel(k3p.a, k3p.b, tbase + (uint32_t)c);
        const double sc = lt[c] + g;
        if (c == 0 || sc > tbest) { tbest = sc; tsel = c; }
      }
      const size_t o = 2236416 + ((size_t)mol * 62 + e) * 4;
      #pragma unroll
      for (int c = 0; c < 4; ++c) out[o + c] = (c == tsel) ? 1.f : 0.f;
    }
  }
}

extern "C" void kernel_launch(void* const* d_in, const int* in_sizes, int n_in,
                              void* d_out, int out_size, void* d_ws, size_t ws_size,
                              hipStream_t stream) {
  (void)in_sizes; (void)n_in; (void)out_size; (void)d_ws; (void)ws_size;
  hipLaunchKernelGGL(gen_kernel, dim3(512), dim3(256), 0, stream,
                     (const float*)d_in[0],  (const float*)d_in[1],
                     (const float*)d_in[2],  (const float*)d_in[3],
                     (const float*)d_in[4],
                     (const float*)d_in[7],  (const float*)d_in[8],
                     (const float*)d_in[9],  (const float*)d_in[10],
                     (const float*)d_in[11], (const float*)d_in[12],
                     (const float*)d_in[13], (const float*)d_in[14],
                     (const float*)d_in[15], (const float*)d_in[16],
                     (const float*)d_in[17], (const float*)d_in[18],
                     (const float*)d_in[19], (const float*)d_in[20],
                     (float*)d_out);
}

// Round 11
// 186.315 us; speedup vs baseline: 1.3270x; 1.3270x over previous
//
#include <hip/hip_runtime.h>
#include <stdint.h>
#include <math.h>

// ---------------------------------------------------------------------------
// Generator_44555990728950. B=4096 molecules, N=32 nodes (chain), H=128,
// 16 GAT layers. All 32 nodes of a molecule are identical through the GAT
// stack, so: layer = relu(x + x@W + b), one class per molecule.
// R17: fp64 MFMA (R16) + RUNTIME D-LAYOUT PROBE.
//   R16 failed (absmax 1.24): assumed C/D mapping row=4*(lane>>4)+reg is
//   HW-verified for bf16..i8 but NOT for the legacy f64 16x16x4 opcode.
//   Fix: two probe MFMAs recover (row, col) of every (lane, reg) at runtime:
//     P_row = MFMA(A[i][k]=i,      B[k][j]=d(k==0)) -> P_row[b] = row(lane,b)
//     P_col = MFMA(A[i][k]=d(k==0),B[k][j]=j)       -> P_col[b] = col(lane,b)
//   Epilogue (bias/residual/store) indexes LDS via rowOf/colOf -> correct
//   under ANY D layout; only the CDNA-universal A/B input layouts assumed.
//   Block = 16 mols, 4 waves; wave owns 32 cols = 2 tiles x 32 K-steps =
//   64 mfma/layer. X in LDS [col][mol] stride 18. 2 barriers/layer.
//   Floor: 17*64*64 cyc = ~29 us MFMA-bound (78.6 TF fp64 matrix).
// Deterministic pipeline fp64 (mfma k-order reassociation ~1e-16); JAX
// partitionable threefry bit-exact; outputs fp32.
// ---------------------------------------------------------------------------

typedef double d4 __attribute__((ext_vector_type(4)));

struct U2 { uint32_t a, b; };

// Threefry-2x32, 20 rounds, exactly as jax._src.prng
__device__ __forceinline__ U2 threefry(uint32_t k0, uint32_t k1, uint32_t x0, uint32_t x1) {
  const uint32_t ks2 = k0 ^ k1 ^ 0x1BD11BDAu;
#define TFR(r) { x0 += x1; x1 = (x1 << (r)) | (x1 >> (32 - (r))); x1 ^= x0; }
  x0 += k0;  x1 += k1;
  TFR(13) TFR(15) TFR(26) TFR(6)
  x0 += k1;  x1 += ks2 + 1u;
  TFR(17) TFR(29) TFR(16) TFR(24)
  x0 += ks2; x1 += k0 + 2u;
  TFR(13) TFR(15) TFR(26) TFR(6)
  x0 += k0;  x1 += k1 + 3u;
  TFR(17) TFR(29) TFR(16) TFR(24)
  x0 += k1;  x1 += ks2 + 4u;
  TFR(13) TFR(15) TFR(26) TFR(6)
  x0 += ks2; x1 += k0 + 5u;
#undef TFR
  U2 r; r.a = x0; r.b = x1; return r;
}

// partitionable random_bits, 32-bit: counter = flat index; fold o1^o2
__device__ __forceinline__ uint32_t pbits(uint32_t k0, uint32_t k1, uint32_t ctr) {
  U2 r = threefry(k0, k1, 0u, ctr);
  return r.a ^ r.b;
}

__device__ __forceinline__ float bits_to_unit(uint32_t bits) {
  return __uint_as_float((bits >> 9) | 0x3f800000u) - 1.0f;  // [0,1)
}

// f32 uniform(1e-6, 1-1e-6) -> gumbel, exactly jax's f32 path
__device__ __forceinline__ float jgumbel(uint32_t k0, uint32_t k1, uint32_t ctr) {
  const float minv = 1e-6f;
  const float maxv = (float)(1.0 - 1e-6);
  const float span = maxv - minv;
  float f = bits_to_unit(pbits(k0, k1, ctr));
  float u = fmaxf(minv, __fadd_rn(__fmul_rn(f, span), minv));
  return -logf(-logf(u));
}

extern "C" __global__ void __launch_bounds__(256)
gen_kernel(const float* __restrict__ noise,
           const float* __restrict__ w1,
           const float* __restrict__ b1,
           const float* __restrict__ gat_w,
           const float* __restrict__ gat_b,
           const float* __restrict__ w_atom,
           const float* __restrict__ b_atom,
           const float* __restrict__ w_hyb,
           const float* __restrict__ b_hyb,
           const float* __restrict__ w_deg,
           const float* __restrict__ b_deg,
           const float* __restrict__ w_chg,
           const float* __restrict__ b_chg,
           const float* __restrict__ w_arom,
           const float* __restrict__ b_arom,
           const float* __restrict__ w_eex,
           const float* __restrict__ b_eex,
           const float* __restrict__ w_ety,
           const float* __restrict__ b_ety,
           float* __restrict__ out)
{
  // X[c][mol], stride 18 doubles
  __shared__ __align__(16) double sX[128][18];     // 18.4 KB
  __shared__ double sScr[16][16];                  // head logits, 2 KB
  __shared__ float  sNF[16][32][17];               // node features, 34.8 KB
  __shared__ double sLP[16][64];                   // lp scratch, 8 KB

  const int t       = threadIdx.x;
  const int wv      = t >> 6;
  const int ln      = t & 63;
  const int g       = ln >> 4;                     // k-slice within K-tile
  const int i       = ln & 15;                     // row/col within tile
  const int molBase = blockIdx.x * 16;
  const int colb    = wv << 5;                     // wave's 32-col slice

  // ---------------- runtime D-layout probe (A/B layouts per CDNA spec)
  int rowOf[4], colOf[4];
  {
    d4 z4 = {0.0, 0.0, 0.0, 0.0};
    const double selK0 = (g == 0) ? 1.0 : 0.0;     // delta(k==0) fragment
    const double idxv  = (double)i;                // i for A-probe, j for B-probe
    d4 prow = __builtin_amdgcn_mfma_f64_16x16x4f64(idxv,  selK0, z4, 0, 0, 0);
    d4 pcol = __builtin_amdgcn_mfma_f64_16x16x4f64(selK0, idxv,  z4, 0, 0, 0);
    #pragma unroll
    for (int j = 0; j < 4; ++j) {
      rowOf[j] = (int)prow[j];
      colOf[j] = (int)pcol[j];
    }
  }

  // ---------------- stage noise transposed into sX[c][mol]
  #pragma unroll
  for (int it = 0; it < 8; ++it) {
    const int idx = t + (it << 8);
    const int c = idx & 127, m = idx >> 7;
    sX[c][m] = (double)noise[(((size_t)(molBase + m)) << 7) + c];
  }
  __syncthreads();

  // ---------------- 17 unified layers via fp64 MFMA:
  //   l==0 : X = relu(noise @ w1 + b1)
  //   l>=1 : X = relu(X + X@W_l + b_l)
  #pragma unroll 1
  for (int l = 0; l < 17; ++l) {
    const float* __restrict__ W  = (l == 0) ? w1 : (gat_w + (((size_t)(l - 1)) << 14));
    const float* __restrict__ bp = (l == 0) ? b1 : (gat_b + ((l - 1) << 7));

    d4 acc0 = {0.0, 0.0, 0.0, 0.0};
    d4 acc1 = {0.0, 0.0, 0.0, 0.0};

    #pragma unroll
    for (int ks = 0; ks < 32; ++ks) {
      const int kk = (ks << 2) + g;                    // this lane's k
      const double a   = sX[kk][i];                    // A: X[mol=i][k=kk]
      const double wb0 = (double)W[(kk << 7) + colb + i];        // B: W[k][col]
      const double wb1 = (double)W[(kk << 7) + colb + 16 + i];
      acc0 = __builtin_amdgcn_mfma_f64_16x16x4f64(a, wb0, acc0, 0, 0, 0);
      acc1 = __builtin_amdgcn_mfma_f64_16x16x4f64(a, wb1, acc1, 0, 0, 0);
    }

    // layout-agnostic epilogue: element (lane, reg j) sits at
    // (mol = rowOf[j], col = colb + colOf[j]) / (+16 for tile 1)
    double nv0[4], nv1[4];
    #pragma unroll
    for (int j = 0; j < 4; ++j) {
      const int cc0 = colb + colOf[j];
      const int cc1 = cc0 + 16;
      double t0 = acc0[j] + (double)bp[cc0];
      double t1 = acc1[j] + (double)bp[cc1];
      if (l > 0) {
        t0 += sX[cc0][rowOf[j]];
        t1 += sX[cc1][rowOf[j]];
      }
      nv0[j] = fmax(t0, 0.0);
      nv1[j] = fmax(t1, 0.0);
    }
    __syncthreads();          // all waves done reading old X
    #pragma unroll
    for (int j = 0; j < 4; ++j) {
      sX[colb + colOf[j]][rowOf[j]]      = nv0[j];
      sX[colb + 16 + colOf[j]][rowOf[j]] = nv1[j];
    }
    __syncthreads();          // new X visible to all waves
  }

  // ---------------- phase A: head logits, 256 threads = 16 mols x 16 heads
  {
    const int mh = t >> 4;             // mol 0..15
    const int h  = t & 15;             // head index
    const float* wp; int stride; double bias;
    if (h < 10)       { wp = w_atom + h;        stride = 10; bias = (double)b_atom[h]; }
    else if (h < 13)  { wp = w_hyb + (h - 10);  stride = 3;  bias = (double)b_hyb[h - 10]; }
    else if (h == 13) { wp = w_deg;             stride = 1;  bias = (double)b_deg[0]; }
    else if (h == 14) { wp = w_chg;             stride = 1;  bias = (double)b_chg[0]; }
    else              { wp = w_arom;            stride = 1;  bias = (double)b_arom[0]; }
    double acc = 0.0;
    for (int c = 0; c < 128; ++c)
      acc = fma(sX[c][mh], (double)wp[c * stride], acc);
    sScr[mh][h] = acc + bias;
  }
  __syncthreads();

  // partitionable split(key(42),4): child_i = threefry((0,42),(0,i))
  const U2 k0p = threefry(0u, 42u, 0u, 0u);
  const U2 k1p = threefry(0u, 42u, 0u, 1u);
  const U2 k2p = threefry(0u, 42u, 0u, 2u);
  const U2 k3p = threefry(0u, 42u, 0u, 3u);

  // ---------------- phase B: per-node sampling, 2 rounds of (8 mols x 32 nodes)
  for (int r = 0; r < 2; ++r) {
    const int mloc = (r << 3) + (t >> 5);
    const int n    = t & 31;
    const int mol  = molBase + mloc;
    const double* scr = sScr[mloc];       // same logits for every node

    double m = scr[0];
    #pragma unroll
    for (int a = 1; a < 10; ++a) m = fmax(m, scr[a]);
    double lsum = 0.0;
    #pragma unroll
    for (int a = 0; a < 10; ++a) lsum += exp(scr[a] - m);
    const double lse = log(lsum);
    const uint32_t abase = ((uint32_t)mol * 32u + (uint32_t)n) * 10u;
    int asel = 0; double abest = 0.0;
    #pragma unroll
    for (int a = 0; a < 10; ++a) {
      const double gg = (double)jgumbel(k0p.a, k0p.b, abase + (uint32_t)a);
      const double sc = scr[a] + gg;
      if (a == 0 || sc > abest) { abest = sc; asel = a; }
    }
    sLP[mloc][n] = (scr[asel] - m) - lse;

    double m2 = fmax(fmax(scr[10], scr[11]), scr[12]);
    double ls2 = exp(scr[10] - m2) + exp(scr[11] - m2) + exp(scr[12] - m2);
    const double lse2 = log(ls2);
    const uint32_t hbase = ((uint32_t)mol * 32u + (uint32_t)n) * 3u;
    int hsel = 0; double hbest = 0.0;
    #pragma unroll
    for (int j = 0; j < 3; ++j) {
      const double gg = (double)jgumbel(k1p.a, k1p.b, hbase + (uint32_t)j);
      const double sc = scr[10 + j] + gg;
      if (j == 0 || sc > hbest) { hbest = sc; hsel = j; }
    }
    sLP[mloc][32 + n] = (scr[10 + hsel] - m2) - lse2;

    const double deg = 1.0 / (1.0 + exp(-scr[13]));
    const double chg = tanh(scr[14]);
    const double pr  = 1.0 / (1.0 + exp(-scr[15]));
    const uint32_t ridx = (uint32_t)mol * 32u + (uint32_t)n;
    const double uu = (double)bits_to_unit(pbits(k2p.a, k2p.b, ridx));
    const double arom = (uu < pr) ? 1.0 : 0.0;
    const double valt[10] = {4.0/5.0, 3.0/5.0, 2.0/5.0, 1.0/5.0, 4.0/5.0,
                             2.0/5.0, 6.0/5.0, 1.0/5.0, 4.0/5.0, 4.0/5.0};
    double nf[17];
    #pragma unroll
    for (int q = 0; q < 10; ++q) nf[q] = (q == asel) ? 1.0 : 0.0;
    nf[10] = deg; nf[11] = chg;
    #pragma unroll
    for (int j = 0; j < 3; ++j) nf[12 + j] = (j == hsel) ? 1.0 : 0.0;
    nf[15] = arom; nf[16] = valt[asel];

    const size_t o = ((size_t)mol * 32 + n) * 17;
    #pragma unroll
    for (int q = 0; q < 17; ++q) {
      sNF[mloc][n][q] = (float)nf[q];
      out[o + q] = (float)nf[q];
    }
  }
  __syncthreads();

  // ---------------- phase C: lp means + edge heads; 4 rounds x 4 waves
  #pragma unroll 1
  for (int r = 0; r < 4; ++r) {
    const int mloc = (r << 2) + wv;
    const int mol  = molBase + mloc;
    if (ln == 62) {
      double sa = 0.0;
      for (int n = 0; n < 32; ++n) sa += sLP[mloc][n];
      out[2228224 + (size_t)mol] = (float)(sa / 32.0);
    } else if (ln == 63) {
      double sh = 0.0;
      for (int n = 0; n < 32; ++n) sh += sLP[mloc][32 + n];
      out[2232320 + (size_t)mol] = (float)(sh / 32.0);
    } else {
      const int e = ln;                       // 0..61
      const int nu_ = (e < 31) ? e : (e - 30);
      const int nv_ = (e < 31) ? (e + 1) : (e - 31);
      double lex = 0.0;
      double lt[4] = {0.0, 0.0, 0.0, 0.0};
      for (int q = 0; q < 17; ++q) {
        const double f = (double)sNF[mloc][nu_][q];
        lex = fma(f, (double)w_eex[q], lex);
        #pragma unroll
        for (int c = 0; c < 4; ++c) lt[c] = fma(f, (double)w_ety[q * 4 + c], lt[c]);
      }
      for (int q = 0; q < 17; ++q) {
        const double f = (double)sNF[mloc][nv_][q];
        lex = fma(f, (double)w_eex[17 + q], lex);
        #pragma unroll
        for (int c = 0; c < 4; ++c) lt[c] = fma(f, (double)w_ety[(17 + q) * 4 + c], lt[c]);
      }
      lex += (double)b_eex[0];
      #pragma unroll
      for (int c = 0; c < 4; ++c) lt[c] += (double)b_ety[c];

      const double pex = 1.0 / (1.0 + exp(-lex));
      out[3252224 + (size_t)mol * 62 + e] = (pex > 0.5) ? 1.f : 0.f;

      const uint32_t tbase = ((uint32_t)mol * 62u + (uint32_t)e) * 4u;
      int tsel = 0; double tbest = 0.0;
      #pragma unroll
      for (int c = 0; c < 4; ++c) {
        const double gg = (double)jgumbel(k3p.a, k3p.b, tbase + (uint32_t)c);
        const double sc = lt[c] + gg;
        if (c == 0 || sc > tbest) { tbest = sc; tsel = c; }
      }
      const size_t o = 2236416 + ((size_t)mol * 62 + e) * 4;
      #pragma unroll
      for (int c = 0; c < 4; ++c) out[o + c] = (c == tsel) ? 1.f : 0.f;
    }
  }
}

extern "C" void kernel_launch(void* const* d_in, const int* in_sizes, int n_in,
                              void* d_out, int out_size, void* d_ws, size_t ws_size,
                              hipStream_t stream) {
  (void)in_sizes; (void)n_in; (void)out_size; (void)d_ws; (void)ws_size;
  hipLaunchKernelGGL(gen_kernel, dim3(256), dim3(256), 0, stream,
                     (const float*)d_in[0],  (const float*)d_in[1],
                     (const float*)d_in[2],  (const float*)d_in[3],
                     (const float*)d_in[4],
                     (const float*)d_in[7],  (const float*)d_in[8],
                     (const float*)d_in[9],  (const float*)d_in[10],
                     (const float*)d_in[11], (const float*)d_in[12],
                     (const float*)d_in[13], (const float*)d_in[14],
                     (const float*)d_in[15], (const float*)d_in[16],
                     (const float*)d_in[17], (const float*)d_in[18],
                     (const float*)d_in[19], (const float*)d_in[20],
                     (float*)d_out);
}

// Round 12
// 178.742 us; speedup vs baseline: 1.3832x; 1.0424x over previous
//
#include <hip/hip_runtime.h>
#include <stdint.h>
#include <math.h>

// ---------------------------------------------------------------------------
// Generator_44555990728950. B=4096 molecules, N=32 nodes (chain), H=128,
// 16 GAT layers. All 32 nodes of a molecule are identical through the GAT
// stack, so: layer = relu(x + x@W + b), one class per molecule.
// R18: R17 (fp64 MFMA + runtime D-layout probe) + 8-wave blocks + 1-barrier
//   layers.
//   R17 post-mortem: PASSED at 100.7us, MfmaUtil 27% ~= the 29us MFMA floor
//   over the measured time; 70% is feed stalls at 1 wave/SIMD (grid 256 =
//   1 block/CU, Occupancy 10.5%). Fix:
//   - 512-thread blocks (8 waves), wave owns 16 cols = 1 tile = 32 MFMA/layer
//     (one acc chain, 8 acc VGPRs); 256 blocks x 8 waves = 2 waves/SIMD ->
//     waves interleave MFMA issue while siblings stall (m114 co-scheduling).
//   - X double-buffered in LDS (sX[2][128][18], ~82KB total): layer l reads
//     buf p, writes buf p^1 -> ONE barrier/layer (17 vs 34).
//   Probe-based layout-agnostic epilogue unchanged from R17 (proven).
// Deterministic pipeline fp64 (mfma k-order reassociation ~1e-16); JAX
// partitionable threefry bit-exact; outputs fp32.
// ---------------------------------------------------------------------------

typedef double d4 __attribute__((ext_vector_type(4)));

struct U2 { uint32_t a, b; };

// Threefry-2x32, 20 rounds, exactly as jax._src.prng
__device__ __forceinline__ U2 threefry(uint32_t k0, uint32_t k1, uint32_t x0, uint32_t x1) {
  const uint32_t ks2 = k0 ^ k1 ^ 0x1BD11BDAu;
#define TFR(r) { x0 += x1; x1 = (x1 << (r)) | (x1 >> (32 - (r))); x1 ^= x0; }
  x0 += k0;  x1 += k1;
  TFR(13) TFR(15) TFR(26) TFR(6)
  x0 += k1;  x1 += ks2 + 1u;
  TFR(17) TFR(29) TFR(16) TFR(24)
  x0 += ks2; x1 += k0 + 2u;
  TFR(13) TFR(15) TFR(26) TFR(6)
  x0 += k0;  x1 += k1 + 3u;
  TFR(17) TFR(29) TFR(16) TFR(24)
  x0 += k1;  x1 += ks2 + 4u;
  TFR(13) TFR(15) TFR(26) TFR(6)
  x0 += ks2; x1 += k0 + 5u;
#undef TFR
  U2 r; r.a = x0; r.b = x1; return r;
}

// partitionable random_bits, 32-bit: counter = flat index; fold o1^o2
__device__ __forceinline__ uint32_t pbits(uint32_t k0, uint32_t k1, uint32_t ctr) {
  U2 r = threefry(k0, k1, 0u, ctr);
  return r.a ^ r.b;
}

__device__ __forceinline__ float bits_to_unit(uint32_t bits) {
  return __uint_as_float((bits >> 9) | 0x3f800000u) - 1.0f;  // [0,1)
}

// f32 uniform(1e-6, 1-1e-6) -> gumbel, exactly jax's f32 path
__device__ __forceinline__ float jgumbel(uint32_t k0, uint32_t k1, uint32_t ctr) {
  const float minv = 1e-6f;
  const float maxv = (float)(1.0 - 1e-6);
  const float span = maxv - minv;
  float f = bits_to_unit(pbits(k0, k1, ctr));
  float u = fmaxf(minv, __fadd_rn(__fmul_rn(f, span), minv));
  return -logf(-logf(u));
}

extern "C" __global__ void __launch_bounds__(512)
gen_kernel(const float* __restrict__ noise,
           const float* __restrict__ w1,
           const float* __restrict__ b1,
           const float* __restrict__ gat_w,
           const float* __restrict__ gat_b,
           const float* __restrict__ w_atom,
           const float* __restrict__ b_atom,
           const float* __restrict__ w_hyb,
           const float* __restrict__ b_hyb,
           const float* __restrict__ w_deg,
           const float* __restrict__ b_deg,
           const float* __restrict__ w_chg,
           const float* __restrict__ b_chg,
           const float* __restrict__ w_arom,
           const float* __restrict__ b_arom,
           const float* __restrict__ w_eex,
           const float* __restrict__ b_eex,
           const float* __restrict__ w_ety,
           const float* __restrict__ b_ety,
           float* __restrict__ out)
{
  // X[buf][col][mol], stride 18 doubles; double-buffered across layers
  __shared__ __align__(16) double sX[2][128][18];  // 36.9 KB
  __shared__ double sScr[16][16];                  // head logits, 2 KB
  __shared__ float  sNF[16][32][17];               // node features, 34.8 KB
  __shared__ double sLP[16][64];                   // lp scratch, 8 KB

  const int t       = threadIdx.x;
  const int wv      = t >> 6;                      // 0..7
  const int ln      = t & 63;
  const int g       = ln >> 4;                     // k-slice within K-tile
  const int i       = ln & 15;                     // row/col within tile
  const int molBase = blockIdx.x * 16;
  const int colb    = wv << 4;                     // wave's 16-col slice

  // ---------------- runtime D-layout probe (A/B layouts per CDNA spec)
  int rowOf[4], colOf[4];
  {
    d4 z4 = {0.0, 0.0, 0.0, 0.0};
    const double selK0 = (g == 0) ? 1.0 : 0.0;     // delta(k==0) fragment
    const double idxv  = (double)i;                // i for A-probe, j for B-probe
    d4 prow = __builtin_amdgcn_mfma_f64_16x16x4f64(idxv,  selK0, z4, 0, 0, 0);
    d4 pcol = __builtin_amdgcn_mfma_f64_16x16x4f64(selK0, idxv,  z4, 0, 0, 0);
    #pragma unroll
    for (int j = 0; j < 4; ++j) {
      rowOf[j] = (int)prow[j];
      colOf[j] = (int)pcol[j];
    }
  }

  // ---------------- stage noise transposed into sX[0][c][mol]
  #pragma unroll
  for (int it = 0; it < 4; ++it) {
    const int idx = t + (it << 9);
    const int c = idx & 127, m = idx >> 7;
    sX[0][c][m] = (double)noise[(((size_t)(molBase + m)) << 7) + c];
  }
  __syncthreads();

  // ---------------- 17 unified layers via fp64 MFMA (ping-pong buffers):
  //   l==0 : X = relu(noise @ w1 + b1)
  //   l>=1 : X = relu(X + X@W_l + b_l)
  int p = 0;
  #pragma unroll 1
  for (int l = 0; l < 17; ++l) {
    const float* __restrict__ W  = (l == 0) ? w1 : (gat_w + (((size_t)(l - 1)) << 14));
    const float* __restrict__ bp = (l == 0) ? b1 : (gat_b + ((l - 1) << 7));
    const int q = p ^ 1;

    d4 acc = {0.0, 0.0, 0.0, 0.0};

    #pragma unroll
    for (int ks = 0; ks < 32; ++ks) {
      const int kk = (ks << 2) + g;                    // this lane's k
      const double a  = sX[p][kk][i];                  // A: X[mol=i][k=kk]
      const double wb = (double)W[(kk << 7) + colb + i]; // B: W[k][col]
      acc = __builtin_amdgcn_mfma_f64_16x16x4f64(a, wb, acc, 0, 0, 0);
    }

    // layout-agnostic epilogue: element (lane, reg j) sits at
    // (mol = rowOf[j], col = colb + colOf[j])
    #pragma unroll
    for (int j = 0; j < 4; ++j) {
      const int cc = colb + colOf[j];
      double tv = acc[j] + (double)bp[cc];
      if (l > 0) tv += sX[p][cc][rowOf[j]];
      sX[q][cc][rowOf[j]] = fmax(tv, 0.0);
    }
    __syncthreads();          // new X complete; old buffer free for next layer
    p = q;
  }
  // final X is in sX[p] (p == 1 after 17 layers)

  // ---------------- phase A: head logits, 256 of 512 thr = 16 mols x 16 heads
  if (t < 256) {
    const int mh = t >> 4;             // mol 0..15
    const int h  = t & 15;             // head index
    const float* wp; int stride; double bias;
    if (h < 10)       { wp = w_atom + h;        stride = 10; bias = (double)b_atom[h]; }
    else if (h < 13)  { wp = w_hyb + (h - 10);  stride = 3;  bias = (double)b_hyb[h - 10]; }
    else if (h == 13) { wp = w_deg;             stride = 1;  bias = (double)b_deg[0]; }
    else if (h == 14) { wp = w_chg;             stride = 1;  bias = (double)b_chg[0]; }
    else              { wp = w_arom;            stride = 1;  bias = (double)b_arom[0]; }
    double acc = 0.0;
    for (int c = 0; c < 128; ++c)
      acc = fma(sX[p][c][mh], (double)wp[c * stride], acc);
    sScr[mh][h] = acc + bias;
  }
  __syncthreads();

  // partitionable split(key(42),4): child_i = threefry((0,42),(0,i))
  const U2 k0p = threefry(0u, 42u, 0u, 0u);
  const U2 k1p = threefry(0u, 42u, 0u, 1u);
  const U2 k2p = threefry(0u, 42u, 0u, 2u);
  const U2 k3p = threefry(0u, 42u, 0u, 3u);

  // ---------------- phase B: per-node sampling, 512 thr = 16 mols x 32 nodes
  {
    const int mloc = t >> 5;              // 0..15
    const int n    = t & 31;
    const int mol  = molBase + mloc;
    const double* scr = sScr[mloc];       // same logits for every node

    double m = scr[0];
    #pragma unroll
    for (int a = 1; a < 10; ++a) m = fmax(m, scr[a]);
    double lsum = 0.0;
    #pragma unroll
    for (int a = 0; a < 10; ++a) lsum += exp(scr[a] - m);
    const double lse = log(lsum);
    const uint32_t abase = ((uint32_t)mol * 32u + (uint32_t)n) * 10u;
    int asel = 0; double abest = 0.0;
    #pragma unroll
    for (int a = 0; a < 10; ++a) {
      const double gg = (double)jgumbel(k0p.a, k0p.b, abase + (uint32_t)a);
      const double sc = scr[a] + gg;
      if (a == 0 || sc > abest) { abest = sc; asel = a; }
    }
    sLP[mloc][n] = (scr[asel] - m) - lse;

    double m2 = fmax(fmax(scr[10], scr[11]), scr[12]);
    double ls2 = exp(scr[10] - m2) + exp(scr[11] - m2) + exp(scr[12] - m2);
    const double lse2 = log(ls2);
    const uint32_t hbase = ((uint32_t)mol * 32u + (uint32_t)n) * 3u;
    int hsel = 0; double hbest = 0.0;
    #pragma unroll
    for (int j = 0; j < 3; ++j) {
      const double gg = (double)jgumbel(k1p.a, k1p.b, hbase + (uint32_t)j);
      const double sc = scr[10 + j] + gg;
      if (j == 0 || sc > hbest) { hbest = sc; hsel = j; }
    }
    sLP[mloc][32 + n] = (scr[10 + hsel] - m2) - lse2;

    const double deg = 1.0 / (1.0 + exp(-scr[13]));
    const double chg = tanh(scr[14]);
    const double pr  = 1.0 / (1.0 + exp(-scr[15]));
    const uint32_t ridx = (uint32_t)mol * 32u + (uint32_t)n;
    const double uu = (double)bits_to_unit(pbits(k2p.a, k2p.b, ridx));
    const double arom = (uu < pr) ? 1.0 : 0.0;
    const double valt[10] = {4.0/5.0, 3.0/5.0, 2.0/5.0, 1.0/5.0, 4.0/5.0,
                             2.0/5.0, 6.0/5.0, 1.0/5.0, 4.0/5.0, 4.0/5.0};
    double nf[17];
    #pragma unroll
    for (int q2 = 0; q2 < 10; ++q2) nf[q2] = (q2 == asel) ? 1.0 : 0.0;
    nf[10] = deg; nf[11] = chg;
    #pragma unroll
    for (int j = 0; j < 3; ++j) nf[12 + j] = (j == hsel) ? 1.0 : 0.0;
    nf[15] = arom; nf[16] = valt[asel];

    const size_t o = ((size_t)mol * 32 + n) * 17;
    #pragma unroll
    for (int q2 = 0; q2 < 17; ++q2) {
      sNF[mloc][n][q2] = (float)nf[q2];
      out[o + q2] = (float)nf[q2];
    }
  }
  __syncthreads();

  // ---------------- phase C: lp means + edge heads; 2 rounds x 8 waves
  #pragma unroll 1
  for (int r = 0; r < 2; ++r) {
    const int mloc = (r << 3) + wv;
    const int mol  = molBase + mloc;
    if (ln == 62) {
      double sa = 0.0;
      for (int n = 0; n < 32; ++n) sa += sLP[mloc][n];
      out[2228224 + (size_t)mol] = (float)(sa / 32.0);
    } else if (ln == 63) {
      double sh = 0.0;
      for (int n = 0; n < 32; ++n) sh += sLP[mloc][32 + n];
      out[2232320 + (size_t)mol] = (float)(sh / 32.0);
    } else {
      const int e = ln;                       // 0..61
      const int nu_ = (e < 31) ? e : (e - 30);
      const int nv_ = (e < 31) ? (e + 1) : (e - 31);
      double lex = 0.0;
      double lt[4] = {0.0, 0.0, 0.0, 0.0};
      for (int q2 = 0; q2 < 17; ++q2) {
        const double f = (double)sNF[mloc][nu_][q2];
        lex = fma(f, (double)w_eex[q2], lex);
        #pragma unroll
        for (int c = 0; c < 4; ++c) lt[c] = fma(f, (double)w_ety[q2 * 4 + c], lt[c]);
      }
      for (int q2 = 0; q2 < 17; ++q2) {
        const double f = (double)sNF[mloc][nv_][q2];
        lex = fma(f, (double)w_eex[17 + q2], lex);
        #pragma unroll
        for (int c = 0; c < 4; ++c) lt[c] = fma(f, (double)w_ety[(17 + q2) * 4 + c], lt[c]);
      }
      lex += (double)b_eex[0];
      #pragma unroll
      for (int c = 0; c < 4; ++c) lt[c] += (double)b_ety[c];

      const double pex = 1.0 / (1.0 + exp(-lex));
      out[3252224 + (size_t)mol * 62 + e] = (pex > 0.5) ? 1.f : 0.f;

      const uint32_t tbase = ((uint32_t)mol * 62u + (uint32_t)e) * 4u;
      int tsel = 0; double tbest = 0.0;
      #pragma unroll
      for (int c = 0; c < 4; ++c) {
        const double gg = (double)jgumbel(k3p.a, k3p.b, tbase + (uint32_t)c);
        const double sc = lt[c] + gg;
        if (c == 0 || sc > tbest) { tbest = sc; tsel = c; }
      }
      const size_t o = 2236416 + ((size_t)mol * 62 + e) * 4;
      #pragma unroll
      for (int c = 0; c < 4; ++c) out[o + c] = (c == tsel) ? 1.f : 0.f;
    }
  }
}

extern "C" void kernel_launch(void* const* d_in, const int* in_sizes, int n_in,
                              void* d_out, int out_size, void* d_ws, size_t ws_size,
                              hipStream_t stream) {
  (void)in_sizes; (void)n_in; (void)out_size; (void)d_ws; (void)ws_size;
  hipLaunchKernelGGL(gen_kernel, dim3(256), dim3(512), 0, stream,
                     (const float*)d_in[0],  (const float*)d_in[1],
                     (const float*)d_in[2],  (const float*)d_in[3],
                     (const float*)d_in[4],
                     (const float*)d_in[7],  (const float*)d_in[8],
                     (const float*)d_in[9],  (const float*)d_in[10],
                     (const float*)d_in[11], (const float*)d_in[12],
                     (const float*)d_in[13], (const float*)d_in[14],
                     (const float*)d_in[15], (const float*)d_in[16],
                     (const float*)d_in[17], (const float*)d_in[18],
                     (const float*)d_in[19], (const float*)d_in[20],
                     (float*)d_out);
}